// Round 2
// baseline (573.464 us; speedup 1.0000x reference)
//
#include <hip/hip_runtime.h>
#include <hip/hip_bf16.h>

typedef __bf16 bf16x8 __attribute__((ext_vector_type(8)));
typedef float  f32x4  __attribute__((ext_vector_type(4)));

constexpr int Bb = 4, Ee = 8, Cc = 512, Mm = 1024, Hh = 4096, Tt = 2048;

// XOR swizzle at 16B granularity within a 128B LDS row (T2, guide §6 G4).
__device__ __forceinline__ int swz(int row, int bcol) {
  return row * 128 + (bcol ^ ((row & 7) << 4));
}

// ---------------------------------------------------------------------------
// Prepass: W2 [E][H][M] fp32  ->  W2T [E][M][H] bf16  (transpose + convert)
// ---------------------------------------------------------------------------
__global__ __launch_bounds__(256) void tr_w2_kernel(
    const float* __restrict__ w2, __bf16* __restrict__ w2t, int e0) {
  __shared__ __bf16 tile[64][68];  // [m][h], pad to 136B rows (8B-aligned)
  const int z = blockIdx.z, e = e0 + z;
  const int m0 = blockIdx.x * 64, h0 = blockIdx.y * 64;
  const int tid = threadIdx.x;
  const int cg = tid & 15, rg = tid >> 4;
#pragma unroll
  for (int p = 0; p < 4; ++p) {
    int hl = rg + p * 16;
    f32x4 v = *(const f32x4*)(w2 + (((size_t)e * Hh + h0 + hl) << 10) + m0 + (cg << 2));
#pragma unroll
    for (int i = 0; i < 4; ++i) tile[(cg << 2) + i][hl] = (__bf16)v[i];
  }
  __syncthreads();
#pragma unroll
  for (int p = 0; p < 4; ++p) {
    int ml = rg + p * 16;
    uint2 pk = *(const uint2*)(&tile[ml][cg << 2]);
    *(uint2*)(w2t + ((size_t)z * Mm + m0 + ml) * Hh + h0 + (cg << 2)) = pk;
  }
}

// ---------------------------------------------------------------------------
// fc1: h[z][t][n] = relu( sum_m x[b,e,c,m] * w1[e,n,m] + b1[e,n] )   (bf16 out)
// 128x128 tile, BK=64, 4 waves (2x2), 16x16x32 bf16 MFMA, reg-staged cvt.
// ---------------------------------------------------------------------------
__global__ __launch_bounds__(256) void fc1_kernel(
    const float* __restrict__ x, const float* __restrict__ w1,
    const float* __restrict__ b1, __bf16* __restrict__ hbuf,
    int e0, int t_base, int tcap) {
  __shared__ __align__(16) char smem[2 * 128 * 128];
  char* As = smem;
  char* Bs = smem + 128 * 128;
  const int tid = threadIdx.x, lane = tid & 63, wid = tid >> 6;
  const int wr = wid >> 1, wc = wid & 1;
  const int z = blockIdx.z, e = e0 + z;
  const int tblk = blockIdx.y * 128, nblk = blockIdx.x * 128;
  const int kl = (tid & 7) << 3;  // element col in [0,64)
  const int r0 = tid >> 3;        // 0..31

  const float* aP[4];
  const float* bP[4];
#pragma unroll
  for (int s = 0; s < 4; ++s) {
    int row = r0 + s * 32;
    int t = t_base + tblk + row;
    int bb = t >> 9, cc = t & 511;
    aP[s] = x + ((((size_t)bb * Ee + e) * Cc + cc) << 10) + kl;
    bP[s] = w1 + (((size_t)e * Hh + (nblk + row)) << 10) + kl;
  }

  const f32x4 zero = {0.f, 0.f, 0.f, 0.f};
  f32x4 acc[4][4];
#pragma unroll
  for (int i = 0; i < 4; ++i)
#pragma unroll
    for (int j = 0; j < 4; ++j) acc[i][j] = zero;

  for (int kt = 0; kt < Mm; kt += 64) {
#pragma unroll
    for (int s = 0; s < 4; ++s) {
      int row = r0 + s * 32;
      f32x4 v0 = *(const f32x4*)(aP[s] + kt);
      f32x4 v1 = *(const f32x4*)(aP[s] + kt + 4);
      bf16x8 pa;
      pa[0] = (__bf16)v0[0]; pa[1] = (__bf16)v0[1]; pa[2] = (__bf16)v0[2]; pa[3] = (__bf16)v0[3];
      pa[4] = (__bf16)v1[0]; pa[5] = (__bf16)v1[1]; pa[6] = (__bf16)v1[2]; pa[7] = (__bf16)v1[3];
      *(bf16x8*)(As + swz(row, kl << 1)) = pa;
      f32x4 u0 = *(const f32x4*)(bP[s] + kt);
      f32x4 u1 = *(const f32x4*)(bP[s] + kt + 4);
      bf16x8 pb;
      pb[0] = (__bf16)u0[0]; pb[1] = (__bf16)u0[1]; pb[2] = (__bf16)u0[2]; pb[3] = (__bf16)u0[3];
      pb[4] = (__bf16)u1[0]; pb[5] = (__bf16)u1[1]; pb[6] = (__bf16)u1[2]; pb[7] = (__bf16)u1[3];
      *(bf16x8*)(Bs + swz(row, kl << 1)) = pb;
    }
    __syncthreads();
#pragma unroll
    for (int kk = 0; kk < 2; ++kk) {
      const int kcol = (kk << 6) + ((lane >> 4) << 4);
      bf16x8 af[4], bfr[4];
#pragma unroll
      for (int i = 0; i < 4; ++i) {
        af[i]  = *(const bf16x8*)(As + swz(wr * 64 + i * 16 + (lane & 15), kcol));
        bfr[i] = *(const bf16x8*)(Bs + swz(wc * 64 + i * 16 + (lane & 15), kcol));
      }
#pragma unroll
      for (int i = 0; i < 4; ++i)
#pragma unroll
        for (int j = 0; j < 4; ++j)
          acc[i][j] = __builtin_amdgcn_mfma_f32_16x16x32_bf16(af[i], bfr[j], acc[i][j], 0, 0, 0);
    }
    __syncthreads();
  }

#pragma unroll
  for (int j = 0; j < 4; ++j) {
    int col = nblk + wc * 64 + j * 16 + (lane & 15);
    float bias = b1[(size_t)e * Hh + col];
#pragma unroll
    for (int i = 0; i < 4; ++i) {
      int rbase = tblk + wr * 64 + i * 16 + ((lane >> 4) << 2);
      f32x4 v = acc[i][j];
#pragma unroll
      for (int r = 0; r < 4; ++r) {
        float o = v[r] + bias;
        o = o > 0.f ? o : 0.f;
        hbuf[((size_t)z * tcap + rbase + r) * Hh + col] = (__bf16)o;
      }
    }
  }
}

// ---------------------------------------------------------------------------
// fc2: out[b,e,c,n] = sum_h hbuf[z][t][h] * w2t[z][n][h] + b2[e,n]   (fp32 out)
// ---------------------------------------------------------------------------
__global__ __launch_bounds__(256) void fc2_kernel(
    const __bf16* __restrict__ hbuf, const __bf16* __restrict__ w2t,
    const float* __restrict__ b2, float* __restrict__ out,
    int e0, int t_base, int tcap) {
  __shared__ __align__(16) char smem[2 * 128 * 128];
  char* As = smem;
  char* Bs = smem + 128 * 128;
  const int tid = threadIdx.x, lane = tid & 63, wid = tid >> 6;
  const int wr = wid >> 1, wc = wid & 1;
  const int z = blockIdx.z, e = e0 + z;
  const int tblk = blockIdx.y * 128, nblk = blockIdx.x * 128;
  const int kl = (tid & 7) << 3;
  const int r0 = tid >> 3;

  const __bf16* aP[4];
  const __bf16* bP[4];
#pragma unroll
  for (int s = 0; s < 4; ++s) {
    int row = r0 + s * 32;
    aP[s] = hbuf + ((size_t)z * tcap + tblk + row) * Hh + kl;
    bP[s] = w2t + ((size_t)z * Mm + (nblk + row)) * Hh + kl;
  }

  const f32x4 zero = {0.f, 0.f, 0.f, 0.f};
  f32x4 acc[4][4];
#pragma unroll
  for (int i = 0; i < 4; ++i)
#pragma unroll
    for (int j = 0; j < 4; ++j) acc[i][j] = zero;

  for (int kt = 0; kt < Hh; kt += 64) {
#pragma unroll
    for (int s = 0; s < 4; ++s) {
      int row = r0 + s * 32;
      bf16x8 pa = *(const bf16x8*)(aP[s] + kt);
      *(bf16x8*)(As + swz(row, kl << 1)) = pa;
      bf16x8 pb = *(const bf16x8*)(bP[s] + kt);
      *(bf16x8*)(Bs + swz(row, kl << 1)) = pb;
    }
    __syncthreads();
#pragma unroll
    for (int kk = 0; kk < 2; ++kk) {
      const int kcol = (kk << 6) + ((lane >> 4) << 4);
      bf16x8 af[4], bfr[4];
#pragma unroll
      for (int i = 0; i < 4; ++i) {
        af[i]  = *(const bf16x8*)(As + swz(wr * 64 + i * 16 + (lane & 15), kcol));
        bfr[i] = *(const bf16x8*)(Bs + swz(wc * 64 + i * 16 + (lane & 15), kcol));
      }
#pragma unroll
      for (int i = 0; i < 4; ++i)
#pragma unroll
        for (int j = 0; j < 4; ++j)
          acc[i][j] = __builtin_amdgcn_mfma_f32_16x16x32_bf16(af[i], bfr[j], acc[i][j], 0, 0, 0);
    }
    __syncthreads();
  }

#pragma unroll
  for (int j = 0; j < 4; ++j) {
    int col = nblk + wc * 64 + j * 16 + (lane & 15);
    float bias = b2[(size_t)e * Mm + col];
#pragma unroll
    for (int i = 0; i < 4; ++i) {
      int rloc = tblk + wr * 64 + i * 16 + ((lane >> 4) << 2);
      f32x4 v = acc[i][j];
#pragma unroll
      for (int r = 0; r < 4; ++r) {
        int t = t_base + rloc + r;
        int bb = t >> 9, cc = t & 511;
        out[((((size_t)bb * Ee + e) * Cc + cc) << 10) + col] = v[r] + bias;
      }
    }
  }
}

// ---------------------------------------------------------------------------
extern "C" void kernel_launch(void* const* d_in, const int* in_sizes, int n_in,
                              void* d_out, int out_size, void* d_ws, size_t ws_size,
                              hipStream_t stream) {
  const float* x  = (const float*)d_in[0];
  const float* w1 = (const float*)d_in[1];
  const float* b1 = (const float*)d_in[2];
  const float* w2 = (const float*)d_in[3];
  const float* b2 = (const float*)d_in[4];
  float* out = (float*)d_out;

  const size_t w2t_e = (size_t)Mm * Hh * sizeof(__bf16);  // 8 MiB / expert
  const size_t h_row = (size_t)Hh * sizeof(__bf16);       // 8 KiB / T-row
  const size_t per_e = w2t_e + (size_t)Tt * h_row;        // 24 MiB / expert

  int G = (int)(ws_size / per_e);
  if (G > Ee) G = Ee;

  if (G >= 1) {
    // [W2T: G experts][h: G experts]
    __bf16* w2t = (__bf16*)d_ws;
    __bf16* hb  = (__bf16*)((char*)d_ws + (size_t)G * w2t_e);
    for (int e0 = 0; e0 < Ee; e0 += G) {
      int g = (Ee - e0) < G ? (Ee - e0) : G;
      tr_w2_kernel<<<dim3(Mm / 64, Hh / 64, g), 256, 0, stream>>>(w2, w2t, e0);
      fc1_kernel<<<dim3(Hh / 128, Tt / 128, g), 256, 0, stream>>>(x, w1, b1, hb, e0, 0, Tt);
      fc2_kernel<<<dim3(Mm / 128, Tt / 128, g), 256, 0, stream>>>(hb, w2t, b2, out, e0, 0, Tt);
    }
  } else {
    // Small workspace: one expert at a time, T chunked.
    __bf16* w2t = (__bf16*)d_ws;
    __bf16* hb  = (__bf16*)((char*)d_ws + w2t_e);
    size_t rem = ws_size > w2t_e ? ws_size - w2t_e : 0;
    int Tc = (int)(rem / h_row) & ~127;
    if (Tc > Tt) Tc = Tt;
    if (Tc < 128) Tc = 128;  // floor; ws below ~9 MiB is not expected
    for (int e0 = 0; e0 < Ee; ++e0) {
      tr_w2_kernel<<<dim3(Mm / 64, Hh / 64, 1), 256, 0, stream>>>(w2, w2t, e0);
      for (int t0 = 0; t0 < Tt; t0 += Tc) {
        int tc = (Tt - t0) < Tc ? (Tt - t0) : Tc;
        fc1_kernel<<<dim3(Hh / 128, tc / 128, 1), 256, 0, stream>>>(x, w1, b1, hb, e0, t0, Tc);
        fc2_kernel<<<dim3(Mm / 128, tc / 128, 1), 256, 0, stream>>>(hb, w2t, b2, out, e0, t0, Tc);
      }
    }
  }
}

// Round 3
// 559.868 us; speedup vs baseline: 1.0243x; 1.0243x over previous
//
#include <hip/hip_runtime.h>
#include <hip/hip_bf16.h>

typedef __bf16 bf16x8 __attribute__((ext_vector_type(8)));
typedef float  f32x4  __attribute__((ext_vector_type(4)));

constexpr int Bb = 4, Ee = 8, Cc = 512, Mm = 1024, Hh = 4096, Tt = 2048;
constexpr size_t MiB = 1024 * 1024;

// async global -> LDS, 16B per lane. LDS dest must be wave-uniform base;
// HW writes base + lane*16 (guide §5; m97/m104). Linear both sides (rule #21).
__device__ __forceinline__ void async16(void* lds, const void* g) {
  __builtin_amdgcn_global_load_lds(
      (const __attribute__((address_space(1))) void*)g,
      (__attribute__((address_space(3))) void*)lds, 16, 0, 0);
}

// ---------------------------------------------------------------------------
// Shared GEMM core: C[128x128] += A[128xK] * B[128xK]^T, K-contig rows (ld==K),
// m97 structure: global_load_lds width16, single-buffered LDS, 2 barriers/step.
// ---------------------------------------------------------------------------
__device__ __forceinline__ void gemm_core(
    const __bf16* __restrict__ aT, const __bf16* __restrict__ bT, int K,
    __bf16 (*As)[64], __bf16 (*Bs)[64], f32x4 (&acc)[4][4],
    int lane, int wid, int wr, int wc) {
  const int l8 = lane >> 3;          // row within 8-row stripe
  const int c8 = (lane & 7) * 8;     // elem col within 64
  const int rbase = wid * 32;        // this wave's 32 LDS rows
  const size_t rowOffA = (size_t)(rbase + l8) * K + c8;

  for (int kt = 0; kt < K; kt += 64) {
#pragma unroll
    for (int i = 0; i < 4; ++i) {
      const int rA = rbase + i * 8;
      async16(&As[rA][0], aT + rowOffA + (size_t)i * 8 * K + kt);
      async16(&Bs[rA][0], bT + rowOffA + (size_t)i * 8 * K + kt);
    }
    __syncthreads();  // compiler drains vmcnt(0) before s_barrier
#pragma unroll
    for (int kk = 0; kk < 2; ++kk) {
      bf16x8 af[4], bg[4];
#pragma unroll
      for (int i = 0; i < 4; ++i) {
        af[i] = *(const bf16x8*)&As[wr * 64 + i * 16 + (lane & 15)][kk * 32 + (lane >> 4) * 8];
        bg[i] = *(const bf16x8*)&Bs[wc * 64 + i * 16 + (lane & 15)][kk * 32 + (lane >> 4) * 8];
      }
#pragma unroll
      for (int i = 0; i < 4; ++i)
#pragma unroll
        for (int j = 0; j < 4; ++j)
          acc[i][j] = __builtin_amdgcn_mfma_f32_16x16x32_bf16(af[i], bg[j], acc[i][j], 0, 0, 0);
    }
    __syncthreads();
  }
}

// ---------------------------------------------------------------------------
// fc1: h = relu(xb @ w1b^T + b1), bf16 out into hb (group-local z).
// Buffer expert index = eOff + z (abs or group-local); bias index = e0 + z.
// ---------------------------------------------------------------------------
__global__ __launch_bounds__(256) void fc1g_kernel(
    const __bf16* __restrict__ xb, int eOffA,
    const __bf16* __restrict__ w1b, int eOffB,
    const float* __restrict__ b1, __bf16* __restrict__ hb,
    int e0, int t_base, int tcap) {
  __shared__ __align__(16) __bf16 As[128][64];
  __shared__ __align__(16) __bf16 Bs[128][64];
  const int tid = threadIdx.x, lane = tid & 63, wid = tid >> 6;
  const int wr = wid >> 1, wc = wid & 1;
  const int z = blockIdx.z;
  const int tblk = blockIdx.y * 128, nblk = blockIdx.x * 128;

  const __bf16* aT = xb + ((size_t)(eOffA + z) * Tt + t_base + tblk) * Mm;
  const __bf16* bT = w1b + ((size_t)(eOffB + z) * Hh + nblk) * Mm;

  f32x4 acc[4][4];
#pragma unroll
  for (int i = 0; i < 4; ++i)
#pragma unroll
    for (int j = 0; j < 4; ++j) acc[i][j] = (f32x4){0.f, 0.f, 0.f, 0.f};

  gemm_core(aT, bT, Mm, As, Bs, acc, lane, wid, wr, wc);

  const float* bias = b1 + (size_t)(e0 + z) * Hh;
#pragma unroll
  for (int j = 0; j < 4; ++j) {
    int col = nblk + wc * 64 + j * 16 + (lane & 15);
    float bv = bias[col];
#pragma unroll
    for (int i = 0; i < 4; ++i) {
      int rbase = tblk + wr * 64 + i * 16 + ((lane >> 4) << 2);
      f32x4 v = acc[i][j];
#pragma unroll
      for (int r = 0; r < 4; ++r) {
        float o = v[r] + bv;
        o = o > 0.f ? o : 0.f;
        hb[((size_t)z * tcap + rbase + r) * Hh + col] = (__bf16)o;
      }
    }
  }
}

// ---------------------------------------------------------------------------
// fc2: out = hb @ w2t^T + b2, fp32 out scattered to [B,E,C,M].
// ---------------------------------------------------------------------------
__global__ __launch_bounds__(256) void fc2g_kernel(
    const __bf16* __restrict__ hb, int tcap,
    const __bf16* __restrict__ w2t, int eOffB,
    const float* __restrict__ b2, float* __restrict__ out,
    int e0, int t_base) {
  __shared__ __align__(16) __bf16 As[128][64];
  __shared__ __align__(16) __bf16 Bs[128][64];
  const int tid = threadIdx.x, lane = tid & 63, wid = tid >> 6;
  const int wr = wid >> 1, wc = wid & 1;
  const int z = blockIdx.z, e = e0 + z;
  const int tblk = blockIdx.y * 128, nblk = blockIdx.x * 128;

  const __bf16* aT = hb + ((size_t)z * tcap + tblk) * Hh;
  const __bf16* bT = w2t + ((size_t)(eOffB + z) * Mm + nblk) * Hh;

  f32x4 acc[4][4];
#pragma unroll
  for (int i = 0; i < 4; ++i)
#pragma unroll
    for (int j = 0; j < 4; ++j) acc[i][j] = (f32x4){0.f, 0.f, 0.f, 0.f};

  gemm_core(aT, bT, Hh, As, Bs, acc, lane, wid, wr, wc);

  const float* bias = b2 + (size_t)e * Mm;
#pragma unroll
  for (int j = 0; j < 4; ++j) {
    int col = nblk + wc * 64 + j * 16 + (lane & 15);
    float bv = bias[col];
#pragma unroll
    for (int i = 0; i < 4; ++i) {
      int rloc = tblk + wr * 64 + i * 16 + ((lane >> 4) << 2);
      f32x4 v = acc[i][j];
#pragma unroll
      for (int r = 0; r < 4; ++r) {
        int t = t_base + rloc + r;
        int bb = t >> 9, cc = t & 511;
        out[((((size_t)bb * Ee + e) * Cc + cc) << 10) + col] = v[r] + bv;
      }
    }
  }
}

// ---------------------------------------------------------------------------
// Prepass: x [B,E,C,M] fp32 -> xb [z][T][M] bf16 (permute fused). 8 elems/thread.
// Grid covers g experts: g * 2^18 / 256 blocks.
// ---------------------------------------------------------------------------
__global__ __launch_bounds__(256) void cvt_x_kernel(
    const float* __restrict__ x, __bf16* __restrict__ xb, int e0) {
  size_t idx8 = (size_t)blockIdx.x * 256 + threadIdx.x;
  int m8 = (int)(idx8 & 127);
  int t = (int)((idx8 >> 7) & 2047);
  int z = (int)(idx8 >> 18);
  int b = t >> 9, c = t & 511, e = e0 + z;
  const float* src = x + ((((size_t)b * Ee + e) * Cc + c) << 10) + (m8 << 3);
  f32x4 v0 = *(const f32x4*)src;
  f32x4 v1 = *(const f32x4*)(src + 4);
  bf16x8 o;
  o[0] = (__bf16)v0[0]; o[1] = (__bf16)v0[1]; o[2] = (__bf16)v0[2]; o[3] = (__bf16)v0[3];
  o[4] = (__bf16)v1[0]; o[5] = (__bf16)v1[1]; o[6] = (__bf16)v1[2]; o[7] = (__bf16)v1[3];
  *(bf16x8*)(xb + (idx8 << 3)) = o;
}

// Pure linear fp32 -> bf16 convert (for w1). count = blocks*2048 elems.
__global__ __launch_bounds__(256) void cvt_lin_kernel(
    const float* __restrict__ in, __bf16* __restrict__ outb) {
  size_t i8 = (size_t)blockIdx.x * 256 + threadIdx.x;
  const float* src = in + (i8 << 3);
  f32x4 v0 = *(const f32x4*)src;
  f32x4 v1 = *(const f32x4*)(src + 4);
  bf16x8 o;
  o[0] = (__bf16)v0[0]; o[1] = (__bf16)v0[1]; o[2] = (__bf16)v0[2]; o[3] = (__bf16)v0[3];
  o[4] = (__bf16)v1[0]; o[5] = (__bf16)v1[1]; o[6] = (__bf16)v1[2]; o[7] = (__bf16)v1[3];
  *(bf16x8*)(outb + (i8 << 3)) = o;
}

// ---------------------------------------------------------------------------
// Prepass: W2 [E][H][M] fp32 -> W2T [z][M][H] bf16 (transpose + convert)
// ---------------------------------------------------------------------------
__global__ __launch_bounds__(256) void tr_w2_kernel(
    const float* __restrict__ w2, __bf16* __restrict__ w2t, int e0) {
  __shared__ __bf16 tile[64][68];
  const int z = blockIdx.z, e = e0 + z;
  const int m0 = blockIdx.x * 64, h0 = blockIdx.y * 64;
  const int tid = threadIdx.x;
  const int cg = tid & 15, rg = tid >> 4;
#pragma unroll
  for (int p = 0; p < 4; ++p) {
    int hl = rg + p * 16;
    f32x4 v = *(const f32x4*)(w2 + (((size_t)e * Hh + h0 + hl) << 10) + m0 + (cg << 2));
#pragma unroll
    for (int i = 0; i < 4; ++i) tile[(cg << 2) + i][hl] = (__bf16)v[i];
  }
  __syncthreads();
#pragma unroll
  for (int p = 0; p < 4; ++p) {
    int ml = rg + p * 16;
    uint2 pk = *(const uint2*)(&tile[ml][cg << 2]);
    *(uint2*)(w2t + ((size_t)z * Mm + m0 + ml) * Hh + h0 + (cg << 2)) = pk;
  }
}

// ---------------------------------------------------------------------------
extern "C" void kernel_launch(void* const* d_in, const int* in_sizes, int n_in,
                              void* d_out, int out_size, void* d_ws, size_t ws_size,
                              hipStream_t stream) {
  const float* x  = (const float*)d_in[0];
  const float* w1 = (const float*)d_in[1];
  const float* b1 = (const float*)d_in[2];
  const float* w2 = (const float*)d_in[3];
  const float* b2 = (const float*)d_in[4];
  float* out = (float*)d_out;

  const size_t xbS = (size_t)Tt * Mm * 2;  //  4 MiB / expert
  const size_t w1S = (size_t)Hh * Mm * 2;  //  8 MiB / expert
  const size_t w2S = (size_t)Mm * Hh * 2;  //  8 MiB / expert
  const size_t hbS = (size_t)Tt * Hh * 2;  // 16 MiB / expert
  char* ws = (char*)d_ws;

  if (ws_size >= Ee * (xbS + w1S + w2S + hbS)) {
    // Path A: everything resident (288 MiB). One shot.
    __bf16* xb  = (__bf16*)ws;
    __bf16* w1b = (__bf16*)(ws + Ee * xbS);
    __bf16* w2t = (__bf16*)(ws + Ee * (xbS + w1S));
    __bf16* hb  = (__bf16*)(ws + Ee * (xbS + w1S + w2S));
    cvt_x_kernel<<<Ee * 1024, 256, 0, stream>>>(x, xb, 0);
    cvt_lin_kernel<<<Ee * 2048, 256, 0, stream>>>(w1, w1b);
    tr_w2_kernel<<<dim3(Mm / 64, Hh / 64, Ee), 256, 0, stream>>>(w2, w2t, 0);
    fc1g_kernel<<<dim3(Hh / 128, Tt / 128, Ee), 256, 0, stream>>>(xb, 0, w1b, 0, b1, hb, 0, 0, Tt);
    fc2g_kernel<<<dim3(Mm / 128, Tt / 128, Ee), 256, 0, stream>>>(hb, Tt, w2t, 0, b2, out, 0, 0);
  } else if (ws_size >= Ee * (xbS + w1S + w2S) + hbS) {
    // Path B: all conversions resident (160 MiB); hb grouped.
    __bf16* xb  = (__bf16*)ws;
    __bf16* w1b = (__bf16*)(ws + Ee * xbS);
    __bf16* w2t = (__bf16*)(ws + Ee * (xbS + w1S));
    __bf16* hb  = (__bf16*)(ws + Ee * (xbS + w1S + w2S));
    int Gh = (int)((ws_size - Ee * (xbS + w1S + w2S)) / hbS);
    if (Gh > Ee) Gh = Ee;
    cvt_x_kernel<<<Ee * 1024, 256, 0, stream>>>(x, xb, 0);
    cvt_lin_kernel<<<Ee * 2048, 256, 0, stream>>>(w1, w1b);
    tr_w2_kernel<<<dim3(Mm / 64, Hh / 64, Ee), 256, 0, stream>>>(w2, w2t, 0);
    for (int e0 = 0; e0 < Ee; e0 += Gh) {
      int g = (Ee - e0) < Gh ? (Ee - e0) : Gh;
      fc1g_kernel<<<dim3(Hh / 128, Tt / 128, g), 256, 0, stream>>>(xb, e0, w1b, e0, b1, hb, e0, 0, Tt);
      fc2g_kernel<<<dim3(Mm / 128, Tt / 128, g), 256, 0, stream>>>(hb, Tt, w2t, e0, b2, out, e0, 0);
    }
  } else if (ws_size >= xbS + w1S + w2S + hbS) {
    // Path C: full pipeline grouped by G experts (36 MiB each).
    int G = (int)(ws_size / (xbS + w1S + w2S + hbS));
    if (G > Ee) G = Ee;
    __bf16* xb  = (__bf16*)ws;
    __bf16* w1b = (__bf16*)(ws + (size_t)G * xbS);
    __bf16* w2t = (__bf16*)(ws + (size_t)G * (xbS + w1S));
    __bf16* hb  = (__bf16*)(ws + (size_t)G * (xbS + w1S + w2S));
    for (int e0 = 0; e0 < Ee; e0 += G) {
      int g = (Ee - e0) < G ? (Ee - e0) : G;
      cvt_x_kernel<<<g * 1024, 256, 0, stream>>>(x, xb, e0);
      cvt_lin_kernel<<<g * 2048, 256, 0, stream>>>(w1 + (size_t)e0 * Hh * Mm, w1b);
      tr_w2_kernel<<<dim3(Mm / 64, Hh / 64, g), 256, 0, stream>>>(w2, w2t, e0);
      fc1g_kernel<<<dim3(Hh / 128, Tt / 128, g), 256, 0, stream>>>(xb, 0, w1b, 0, b1, hb, e0, 0, Tt);
      fc2g_kernel<<<dim3(Mm / 128, Tt / 128, g), 256, 0, stream>>>(hb, Tt, w2t, 0, b2, out, e0, 0);
    }
  } else {
    // Path D: one expert, T chunked (needs ~21 MiB).
    __bf16* xb  = (__bf16*)ws;
    __bf16* w1b = (__bf16*)(ws + xbS);
    __bf16* w2t = (__bf16*)(ws + xbS + w1S);
    __bf16* hb  = (__bf16*)(ws + xbS + w1S + w2S);
    size_t rem = ws_size > (xbS + w1S + w2S) ? ws_size - (xbS + w1S + w2S) : 0;
    int Tc = (int)(rem / ((size_t)Hh * 2)) & ~127;
    if (Tc > Tt) Tc = Tt;
    if (Tc < 128) Tc = 128;
    for (int e0 = 0; e0 < Ee; ++e0) {
      cvt_x_kernel<<<1024, 256, 0, stream>>>(x, xb, e0);
      cvt_lin_kernel<<<2048, 256, 0, stream>>>(w1 + (size_t)e0 * Hh * Mm, w1b);
      tr_w2_kernel<<<dim3(Mm / 64, Hh / 64, 1), 256, 0, stream>>>(w2, w2t, e0);
      for (int t0 = 0; t0 < Tt; t0 += Tc) {
        int tc = (Tt - t0) < Tc ? (Tt - t0) : Tc;
        fc1g_kernel<<<dim3(Hh / 128, tc / 128, 1), 256, 0, stream>>>(xb, 0, w1b, 0, b1, hb, e0, t0, Tc);
        fc2g_kernel<<<dim3(Mm / 128, tc / 128, 1), 256, 0, stream>>>(hb, Tc, w2t, 0, b2, out, e0, t0);
      }
    }
  }
}

// Round 4
// 459.130 us; speedup vs baseline: 1.2490x; 1.2194x over previous
//
#include <hip/hip_runtime.h>
#include <hip/hip_bf16.h>

typedef __bf16 bf16x8 __attribute__((ext_vector_type(8)));
typedef float  f32x4  __attribute__((ext_vector_type(4)));

constexpr int Ee = 8, Cc = 512, Mm = 1024, Hh = 4096, Tt = 2048;

// async global->LDS, 16B/lane. LDS dest wave-uniform base + lane*16 (m97/m104).
__device__ __forceinline__ void async16(void* lds, const void* g) {
  __builtin_amdgcn_global_load_lds(
      (const __attribute__((address_space(1))) void*)g,
      (__attribute__((address_space(3))) void*)lds, 16, 0, 0);
}

#define FENCE() asm volatile("" ::: "memory")
#define BARRIER() do { FENCE(); __builtin_amdgcn_s_barrier(); FENCE(); } while (0)

// Bijective XCD-chunked swizzle (m204): contiguous work chunk per XCD.
__device__ __forceinline__ int xcd_swz(int id, int n) {
  const int q = n >> 3, r = n & 7;
  const int x = id & 7, k = id >> 3;
  return (x < r ? x * (q + 1) : r * (q + 1) + (x - r) * q) + k;
}

// ---------------------------------------------------------------------------
// 256x256 GEMM core, BK=64, 8 waves (2M x 4N), phase-split pipeline.
//   C[256x256] += A[256xK] * B[256xK]^T   (rows K-contiguous, K % 64 == 0)
// Pipeline ledger (per wave, 2 gload_lds per half-tile unit):
//   units u0=A-half0, u1=A-half1, u2=B-half0, u3=B-half1; tile t -> dbuf t&1.
//   sigma(t+1,u2)@t.P1, sigma(t+1,u3)@t.P2, sigma(t+2,u0)@t.P3, sigma(t+2,u1)@t.P4.
//   A-LDS of dbuf d free after t.P2 (A reg-cached); B-LDS of dbuf d read thru P4,
//   next write at t+1.P1 (after t.P4 post-barrier) -> no landing race.
//   vmcnt(4) at t.P4 (after sigma(t+2,u1)): only the 2 sigma(t+2) units (4 loads)
//   may be outstanding -> all of tile t+1 landed. Last 2 tiles: vmcnt(0).
// LDS swizzle: 16B block, phys = logical ^ (row&7); staged via pre-swizzled
//   global source (involution both sides, rule #21). 2-way read conflict = free.
// ---------------------------------------------------------------------------
__device__ __forceinline__ void gemm256(
    const __bf16* __restrict__ aT, const __bf16* __restrict__ bT, const int K,
    __bf16 (*Ab)[2][128][64], __bf16 (*Bb)[2][128][64],
    f32x4 (&acc)[8][4]) {
  const int tid = threadIdx.x;
  const int lane = tid & 63, wid = tid >> 6;
  const int wr = wid >> 2, wcn = wid & 3;
  const int l8 = lane >> 3;                    // row within 8-row stage group
  const int colSwzE = (((lane & 7) ^ l8) << 3);  // pre-swizzled source col (elems)
  const int NT = K >> 6;

  int pblk[2];
  pblk[0] = (lane >> 4) ^ (lane & 7);
  pblk[1] = (4 + (lane >> 4)) ^ (lane & 7);

  bf16x8 aF[8][2];   // A frags cached across the whole tile
  bf16x8 bF[2][2];   // B frags per phase

  auto STAGE = [&](int s, int u) {
    if (s >= NT) return;
    const int d = s & 1;
    if (u < 2) {
      const __bf16* src = aT + (size_t)(u * 128 + wid * 16 + l8) * K + s * 64 + colSwzE;
#pragma unroll
      for (int i = 0; i < 2; ++i)
        async16(&Ab[d][u][wid * 16 + i * 8][0], src + (size_t)(i * 8) * K);
    } else {
      const __bf16* src = bT + (size_t)((u - 2) * 128 + wid * 16 + l8) * K + s * 64 + colSwzE;
#pragma unroll
      for (int i = 0; i < 2; ++i)
        async16(&Bb[d][u - 2][wid * 16 + i * 8][0], src + (size_t)(i * 8) * K);
    }
  };

  // prologue: tile0 fully + tile1 A-halves; tile0 landed before first read.
  STAGE(0, 0); STAGE(0, 1); STAGE(0, 2); STAGE(0, 3);
  STAGE(1, 0); STAGE(1, 1);
  asm volatile("s_waitcnt vmcnt(4)" ::: "memory");
  BARRIER();

  for (int t = 0; t < NT; ++t) {
    const int d = t & 1;
    const char* pa = (const char*)&Ab[d][wr][0][0];
    const char* pb = (const char*)&Bb[d][wcn >> 1][0][0];
    const int brow = (wcn & 1) * 64;

    // ---- P1: read A mi0-3 + B ni0-1; stage sigma(t+1, B-half0)
#pragma unroll
    for (int mi = 0; mi < 4; ++mi)
#pragma unroll
      for (int kh = 0; kh < 2; ++kh)
        aF[mi][kh] = *(const bf16x8*)(pa + (mi * 16 + (lane & 15)) * 128 + pblk[kh] * 16);
#pragma unroll
    for (int ni = 0; ni < 2; ++ni)
#pragma unroll
      for (int kh = 0; kh < 2; ++kh)
        bF[ni][kh] = *(const bf16x8*)(pb + (brow + ni * 16 + (lane & 15)) * 128 + pblk[kh] * 16);
    STAGE(t + 1, 2);
    BARRIER();
    __builtin_amdgcn_s_setprio(1);
#pragma unroll
    for (int mi = 0; mi < 4; ++mi)
#pragma unroll
      for (int ni = 0; ni < 2; ++ni)
#pragma unroll
        for (int kh = 0; kh < 2; ++kh)
          acc[mi][ni] = __builtin_amdgcn_mfma_f32_16x16x32_bf16(aF[mi][kh], bF[ni][kh], acc[mi][ni], 0, 0, 0);
    __builtin_amdgcn_s_setprio(0);
    BARRIER();

    // ---- P2: read A mi4-7 + B ni2-3; stage sigma(t+1, B-half1)
#pragma unroll
    for (int mi = 0; mi < 4; ++mi)
#pragma unroll
      for (int kh = 0; kh < 2; ++kh)
        aF[4 + mi][kh] = *(const bf16x8*)(pa + ((4 + mi) * 16 + (lane & 15)) * 128 + pblk[kh] * 16);
#pragma unroll
    for (int ni = 0; ni < 2; ++ni)
#pragma unroll
      for (int kh = 0; kh < 2; ++kh)
        bF[ni][kh] = *(const bf16x8*)(pb + (brow + (2 + ni) * 16 + (lane & 15)) * 128 + pblk[kh] * 16);
    STAGE(t + 1, 3);
    BARRIER();
    __builtin_amdgcn_s_setprio(1);
#pragma unroll
    for (int mi = 0; mi < 4; ++mi)
#pragma unroll
      for (int ni = 0; ni < 2; ++ni)
#pragma unroll
        for (int kh = 0; kh < 2; ++kh)
          acc[4 + mi][2 + ni] = __builtin_amdgcn_mfma_f32_16x16x32_bf16(aF[4 + mi][kh], bF[ni][kh], acc[4 + mi][2 + ni], 0, 0, 0);
    __builtin_amdgcn_s_setprio(0);
    BARRIER();   // <- A-LDS (dbuf d) fully read; safe to stage into it

    // ---- P3: re-read B ni2-3; stage sigma(t+2, A-half0); MFMA mi0-3 x ni2-3
#pragma unroll
    for (int ni = 0; ni < 2; ++ni)
#pragma unroll
      for (int kh = 0; kh < 2; ++kh)
        bF[ni][kh] = *(const bf16x8*)(pb + (brow + (2 + ni) * 16 + (lane & 15)) * 128 + pblk[kh] * 16);
    STAGE(t + 2, 0);
    BARRIER();
    __builtin_amdgcn_s_setprio(1);
#pragma unroll
    for (int mi = 0; mi < 4; ++mi)
#pragma unroll
      for (int ni = 0; ni < 2; ++ni)
#pragma unroll
        for (int kh = 0; kh < 2; ++kh)
          acc[mi][2 + ni] = __builtin_amdgcn_mfma_f32_16x16x32_bf16(aF[mi][kh], bF[ni][kh], acc[mi][2 + ni], 0, 0, 0);
    __builtin_amdgcn_s_setprio(0);
    BARRIER();

    // ---- P4: re-read B ni0-1; stage sigma(t+2, A-half1); counted vmcnt; MFMA mi4-7 x ni0-1
#pragma unroll
    for (int ni = 0; ni < 2; ++ni)
#pragma unroll
      for (int kh = 0; kh < 2; ++kh)
        bF[ni][kh] = *(const bf16x8*)(pb + (brow + ni * 16 + (lane & 15)) * 128 + pblk[kh] * 16);
    STAGE(t + 2, 1);
    if (t < NT - 2) { asm volatile("s_waitcnt vmcnt(4)" ::: "memory"); }
    else            { asm volatile("s_waitcnt vmcnt(0)" ::: "memory"); }
    BARRIER();
    __builtin_amdgcn_s_setprio(1);
#pragma unroll
    for (int mi = 0; mi < 4; ++mi)
#pragma unroll
      for (int ni = 0; ni < 2; ++ni)
#pragma unroll
        for (int kh = 0; kh < 2; ++kh)
          acc[4 + mi][ni] = __builtin_amdgcn_mfma_f32_16x16x32_bf16(aF[4 + mi][kh], bF[ni][kh], acc[4 + mi][ni], 0, 0, 0);
    __builtin_amdgcn_s_setprio(0);
    BARRIER();
  }
}

// ---------------------------------------------------------------------------
// fc1: h = relu(xb @ w1b^T + b1) -> bf16 hb
// ---------------------------------------------------------------------------
__global__ __launch_bounds__(512, 2) void fc1g_kernel(
    const __bf16* __restrict__ xb, int eOffA,
    const __bf16* __restrict__ w1b, int eOffB,
    const float* __restrict__ b1, __bf16* __restrict__ hb,
    int e0, int t_base, int tcap, int nbT) {
  __shared__ __bf16 Ab[2][2][128][64];
  __shared__ __bf16 Bb[2][2][128][64];
  const int nbN = Hh / 256;  // 16
  const int id = xcd_swz(blockIdx.x, gridDim.x);
  const int z = id / (nbN * nbT);
  const int rm = id % (nbN * nbT);
  const int tblk = (rm / nbN) * 256, nblk = (rm % nbN) * 256;
  const int lane = threadIdx.x & 63, wid = threadIdx.x >> 6;
  const int wr = wid >> 2, wcn = wid & 3;

  const __bf16* aT = xb + ((size_t)(eOffA + z) * Tt + t_base + tblk) * Mm;
  const __bf16* bT = w1b + ((size_t)(eOffB + z) * Hh + nblk) * Mm;

  f32x4 acc[8][4];
#pragma unroll
  for (int i = 0; i < 8; ++i)
#pragma unroll
    for (int j = 0; j < 4; ++j) acc[i][j] = (f32x4){0.f, 0.f, 0.f, 0.f};

  gemm256(aT, bT, Mm, Ab, Bb, acc);

  const float* bias = b1 + (size_t)(e0 + z) * Hh;
  const int row0 = tblk + wr * 128 + ((lane >> 4) << 2);
  const int col0 = nblk + wcn * 64 + (lane & 15);
#pragma unroll
  for (int ni = 0; ni < 4; ++ni) {
    const int col = col0 + ni * 16;
    const float bv = bias[col];
#pragma unroll
    for (int mi = 0; mi < 8; ++mi) {
      const int r0 = row0 + mi * 16;
      f32x4 v = acc[mi][ni];
#pragma unroll
      for (int rr = 0; rr < 4; ++rr) {
        float o = v[rr] + bv;
        o = o > 0.f ? o : 0.f;
        hb[((size_t)z * tcap + r0 + rr) * Hh + col] = (__bf16)o;
      }
    }
  }
}

// ---------------------------------------------------------------------------
// fc2: out = hb @ w2t^T + b2 -> fp32 scattered to [B,E,C,M]
// ---------------------------------------------------------------------------
__global__ __launch_bounds__(512, 2) void fc2g_kernel(
    const __bf16* __restrict__ hb, int tcap,
    const __bf16* __restrict__ w2t, int eOffB,
    const float* __restrict__ b2, float* __restrict__ out,
    int e0, int t_base, int nbT) {
  __shared__ __bf16 Ab[2][2][128][64];
  __shared__ __bf16 Bb[2][2][128][64];
  const int nbN = Mm / 256;  // 4
  const int id = xcd_swz(blockIdx.x, gridDim.x);
  const int z = id / (nbN * nbT);
  const int rm = id % (nbN * nbT);
  const int tblk = (rm / nbN) * 256, nblk = (rm % nbN) * 256;
  const int lane = threadIdx.x & 63, wid = threadIdx.x >> 6;
  const int wr = wid >> 2, wcn = wid & 3;
  const int e = e0 + z;

  const __bf16* aT = hb + ((size_t)z * tcap + tblk) * Hh;
  const __bf16* bT = w2t + ((size_t)(eOffB + z) * Mm + nblk) * Hh;

  f32x4 acc[8][4];
#pragma unroll
  for (int i = 0; i < 8; ++i)
#pragma unroll
    for (int j = 0; j < 4; ++j) acc[i][j] = (f32x4){0.f, 0.f, 0.f, 0.f};

  gemm256(aT, bT, Hh, Ab, Bb, acc);

  const float* bias = b2 + (size_t)e * Mm;
  const int row0 = tblk + wr * 128 + ((lane >> 4) << 2);
  const int col0 = nblk + wcn * 64 + (lane & 15);
#pragma unroll
  for (int ni = 0; ni < 4; ++ni) {
    const int col = col0 + ni * 16;
    const float bv = bias[col];
#pragma unroll
    for (int mi = 0; mi < 8; ++mi) {
      const int r0 = row0 + mi * 16;
      f32x4 v = acc[mi][ni];
#pragma unroll
      for (int rr = 0; rr < 4; ++rr) {
        const int t = t_base + r0 + rr;
        const int bb = t >> 9, cc = t & 511;
        out[((((size_t)bb * Ee + e) * Cc + cc) << 10) + col] = v[rr] + bv;
      }
    }
  }
}

// ---------------------------------------------------------------------------
// Prepass: x [B,E,C,M] fp32 -> xb [z][T][M] bf16 (permute fused)
// ---------------------------------------------------------------------------
__global__ __launch_bounds__(256) void cvt_x_kernel(
    const float* __restrict__ x, __bf16* __restrict__ xb, int e0) {
  size_t idx8 = (size_t)blockIdx.x * 256 + threadIdx.x;
  int m8 = (int)(idx8 & 127);
  int t = (int)((idx8 >> 7) & 2047);
  int z = (int)(idx8 >> 18);
  int b = t >> 9, c = t & 511, e = e0 + z;
  const float* src = x + ((((size_t)b * Ee + e) * Cc + c) << 10) + (m8 << 3);
  f32x4 v0 = *(const f32x4*)src;
  f32x4 v1 = *(const f32x4*)(src + 4);
  bf16x8 o;
  o[0] = (__bf16)v0[0]; o[1] = (__bf16)v0[1]; o[2] = (__bf16)v0[2]; o[3] = (__bf16)v0[3];
  o[4] = (__bf16)v1[0]; o[5] = (__bf16)v1[1]; o[6] = (__bf16)v1[2]; o[7] = (__bf16)v1[3];
  *(bf16x8*)(xb + (idx8 << 3)) = o;
}

__global__ __launch_bounds__(256) void cvt_lin_kernel(
    const float* __restrict__ in, __bf16* __restrict__ outb) {
  size_t i8 = (size_t)blockIdx.x * 256 + threadIdx.x;
  const float* src = in + (i8 << 3);
  f32x4 v0 = *(const f32x4*)src;
  f32x4 v1 = *(const f32x4*)(src + 4);
  bf16x8 o;
  o[0] = (__bf16)v0[0]; o[1] = (__bf16)v0[1]; o[2] = (__bf16)v0[2]; o[3] = (__bf16)v0[3];
  o[4] = (__bf16)v1[0]; o[5] = (__bf16)v1[1]; o[6] = (__bf16)v1[2]; o[7] = (__bf16)v1[3];
  *(bf16x8*)(outb + (i8 << 3)) = o;
}

// ---------------------------------------------------------------------------
// Prepass: W2 [E][H][M] fp32 -> W2T [z][M][H] bf16 (transpose + convert)
// ---------------------------------------------------------------------------
__global__ __launch_bounds__(256) void tr_w2_kernel(
    const float* __restrict__ w2, __bf16* __restrict__ w2t, int e0) {
  __shared__ __bf16 tile[64][68];
  const int z = blockIdx.z, e = e0 + z;
  const int m0 = blockIdx.x * 64, h0 = blockIdx.y * 64;
  const int tid = threadIdx.x;
  const int cg = tid & 15, rg = tid >> 4;
#pragma unroll
  for (int p = 0; p < 4; ++p) {
    int hl = rg + p * 16;
    f32x4 v = *(const f32x4*)(w2 + (((size_t)e * Hh + h0 + hl) << 10) + m0 + (cg << 2));
#pragma unroll
    for (int i = 0; i < 4; ++i) tile[(cg << 2) + i][hl] = (__bf16)v[i];
  }
  __syncthreads();
#pragma unroll
  for (int p = 0; p < 4; ++p) {
    int ml = rg + p * 16;
    uint2 pk = *(const uint2*)(&tile[ml][cg << 2]);
    *(uint2*)(w2t + ((size_t)z * Mm + m0 + ml) * Hh + h0 + (cg << 2)) = pk;
  }
}

// ---------------------------------------------------------------------------
extern "C" void kernel_launch(void* const* d_in, const int* in_sizes, int n_in,
                              void* d_out, int out_size, void* d_ws, size_t ws_size,
                              hipStream_t stream) {
  const float* x  = (const float*)d_in[0];
  const float* w1 = (const float*)d_in[1];
  const float* b1 = (const float*)d_in[2];
  const float* w2 = (const float*)d_in[3];
  const float* b2 = (const float*)d_in[4];
  float* out = (float*)d_out;

  const size_t xbS = (size_t)Tt * Mm * 2;  //  4 MiB / expert
  const size_t w1S = (size_t)Hh * Mm * 2;  //  8 MiB / expert
  const size_t w2S = (size_t)Mm * Hh * 2;  //  8 MiB / expert
  const size_t hbS = (size_t)Tt * Hh * 2;  // 16 MiB / expert
  char* ws = (char*)d_ws;

  if (ws_size >= Ee * (xbS + w1S + w2S + hbS)) {
    // Path A: everything resident (288 MiB). One shot.
    __bf16* xb  = (__bf16*)ws;
    __bf16* w1b = (__bf16*)(ws + Ee * xbS);
    __bf16* w2t = (__bf16*)(ws + Ee * (xbS + w1S));
    __bf16* hb  = (__bf16*)(ws + Ee * (xbS + w1S + w2S));
    cvt_x_kernel<<<Ee * 1024, 256, 0, stream>>>(x, xb, 0);
    cvt_lin_kernel<<<Ee * 2048, 256, 0, stream>>>(w1, w1b);
    tr_w2_kernel<<<dim3(Mm / 64, Hh / 64, Ee), 256, 0, stream>>>(w2, w2t, 0);
    fc1g_kernel<<<(Hh / 256) * (Tt / 256) * Ee, 512, 0, stream>>>(xb, 0, w1b, 0, b1, hb, 0, 0, Tt, Tt / 256);
    fc2g_kernel<<<(Mm / 256) * (Tt / 256) * Ee, 512, 0, stream>>>(hb, Tt, w2t, 0, b2, out, 0, 0, Tt / 256);
  } else if (ws_size >= Ee * (xbS + w1S + w2S) + hbS) {
    // Path B: all conversions resident; hb grouped.
    __bf16* xb  = (__bf16*)ws;
    __bf16* w1b = (__bf16*)(ws + Ee * xbS);
    __bf16* w2t = (__bf16*)(ws + Ee * (xbS + w1S));
    __bf16* hb  = (__bf16*)(ws + Ee * (xbS + w1S + w2S));
    int Gh = (int)((ws_size - Ee * (xbS + w1S + w2S)) / hbS);
    if (Gh > Ee) Gh = Ee;
    cvt_x_kernel<<<Ee * 1024, 256, 0, stream>>>(x, xb, 0);
    cvt_lin_kernel<<<Ee * 2048, 256, 0, stream>>>(w1, w1b);
    tr_w2_kernel<<<dim3(Mm / 64, Hh / 64, Ee), 256, 0, stream>>>(w2, w2t, 0);
    for (int e0 = 0; e0 < Ee; e0 += Gh) {
      int g = (Ee - e0) < Gh ? (Ee - e0) : Gh;
      fc1g_kernel<<<(Hh / 256) * (Tt / 256) * g, 512, 0, stream>>>(xb, e0, w1b, e0, b1, hb, e0, 0, Tt, Tt / 256);
      fc2g_kernel<<<(Mm / 256) * (Tt / 256) * g, 512, 0, stream>>>(hb, Tt, w2t, e0, b2, out, e0, 0, Tt / 256);
    }
  } else if (ws_size >= xbS + w1S + w2S + hbS) {
    // Path C: full pipeline grouped by G experts.
    int G = (int)(ws_size / (xbS + w1S + w2S + hbS));
    if (G > Ee) G = Ee;
    __bf16* xb  = (__bf16*)ws;
    __bf16* w1b = (__bf16*)(ws + (size_t)G * xbS);
    __bf16* w2t = (__bf16*)(ws + (size_t)G * (xbS + w1S));
    __bf16* hb  = (__bf16*)(ws + (size_t)G * (xbS + w1S + w2S));
    for (int e0 = 0; e0 < Ee; e0 += G) {
      int g = (Ee - e0) < G ? (Ee - e0) : G;
      cvt_x_kernel<<<g * 1024, 256, 0, stream>>>(x, xb, e0);
      cvt_lin_kernel<<<g * 2048, 256, 0, stream>>>(w1 + (size_t)e0 * Hh * Mm, w1b);
      tr_w2_kernel<<<dim3(Mm / 64, Hh / 64, g), 256, 0, stream>>>(w2, w2t, e0);
      fc1g_kernel<<<(Hh / 256) * (Tt / 256) * g, 512, 0, stream>>>(xb, 0, w1b, 0, b1, hb, e0, 0, Tt, Tt / 256);
      fc2g_kernel<<<(Mm / 256) * (Tt / 256) * g, 512, 0, stream>>>(hb, Tt, w2t, 0, b2, out, e0, 0, Tt / 256);
    }
  } else {
    // Path D: one expert, T chunked (256-row granularity).
    __bf16* xb  = (__bf16*)ws;
    __bf16* w1b = (__bf16*)(ws + xbS);
    __bf16* w2t = (__bf16*)(ws + xbS + w1S);
    __bf16* hb  = (__bf16*)(ws + xbS + w1S + w2S);
    size_t rem = ws_size > (xbS + w1S + w2S) ? ws_size - (xbS + w1S + w2S) : 0;
    int Tc = (int)(rem / ((size_t)Hh * 2)) & ~255;
    if (Tc > Tt) Tc = Tt;
    if (Tc < 256) Tc = 256;
    for (int e0 = 0; e0 < Ee; ++e0) {
      cvt_x_kernel<<<1024, 256, 0, stream>>>(x, xb, e0);
      cvt_lin_kernel<<<2048, 256, 0, stream>>>(w1 + (size_t)e0 * Hh * Mm, w1b);
      tr_w2_kernel<<<dim3(Mm / 64, Hh / 64, 1), 256, 0, stream>>>(w2, w2t, e0);
      for (int t0 = 0; t0 < Tt; t0 += Tc) {
        int tc = (Tt - t0) < Tc ? (Tt - t0) : Tc;
        fc1g_kernel<<<(Hh / 256) * (tc / 256), 512, 0, stream>>>(xb, 0, w1b, 0, b1, hb, e0, t0, Tc, tc / 256);
        fc2g_kernel<<<(Mm / 256) * (tc / 256), 512, 0, stream>>>(hb, Tc, w2t, 0, b2, out, e0, t0, tc / 256);
      }
    }
  }
}

// Round 5
// 426.827 us; speedup vs baseline: 1.3436x; 1.0757x over previous
//
#include <hip/hip_runtime.h>
#include <hip/hip_bf16.h>

typedef __bf16 bf16x8 __attribute__((ext_vector_type(8)));
typedef __bf16 bf16x4 __attribute__((ext_vector_type(4)));
typedef float  f32x4  __attribute__((ext_vector_type(4)));

constexpr int Ee = 8, Cc = 512, Mm = 1024, Hh = 4096, Tt = 2048;

// async global->LDS, 16B/lane. LDS dest wave-uniform base + lane*16 (m97/m104).
__device__ __forceinline__ void async16(void* lds, const void* g) {
  __builtin_amdgcn_global_load_lds(
      (const __attribute__((address_space(1))) void*)g,
      (__attribute__((address_space(3))) void*)lds, 16, 0, 0);
}

#define FENCE() asm volatile("" ::: "memory")
#define BARRIER() do { FENCE(); __builtin_amdgcn_s_barrier(); FENCE(); } while (0)

// Bijective XCD-chunked swizzle (m204).
__device__ __forceinline__ int xcd_swz(int id, int n) {
  const int q = n >> 3, r = n & 7;
  const int x = id & 7, k = id >> 3;
  return (x < r ? x * (q + 1) : r * (q + 1) + (x - r) * q) + k;
}

// ---------------------------------------------------------------------------
// 256x256 GEMM core, BK=64, 8 waves (2M x 4N), 2 barriers per K-tile.
//   acc[mi][ni] = transposed fragments: D = mfma(bF, aF) -> rows=n, cols=t.
// Sync ledger (per tile t, dbuf = parity):
//   B0(entry): stage B(t+1)h0,h1 (B-slot parity (t+1) last read in tile t-1,
//     all reads issued pre-B0; stage-write returns >=200cy later - safe WAR).
//   read aF[0..7] (16) + bF(ni01) (4).
//   B1: separates ALL waves' A(t)-reads from A(t+2) stage issues (same parity).
//   stage A(t+2)h0,h1; 32 MFMA (ni01); read bF(ni23) (4); 32 MFMA (ni23).
//   vmcnt(4): drains B(t+1) (8 outstanding -> keep newest 4 = A(t+2) in
//     flight across the boundary barrier - counted-vmcnt win). Tail: vmcnt(0).
// Prologue: stage A0,B0(8 loads) + A1(4); vmcnt(4) -> tile0 landed; barrier.
// LDS swizzle: 16B block, phys = logical ^ (row&7), via pre-swizzled global
//   source (involution both sides, rule #21). Aggregate-conflict-free reads.
// ---------------------------------------------------------------------------
__device__ __forceinline__ void gemm256(
    const __bf16* __restrict__ aT, const __bf16* __restrict__ bT, const int K,
    __bf16 (*Ab)[2][128][64], __bf16 (*Bb)[2][128][64],
    f32x4 (&acc)[8][4]) {
  const int tid = threadIdx.x;
  const int lane = tid & 63, wid = tid >> 6;
  const int wr = wid >> 2, wcn = wid & 3;
  const int l8 = lane >> 3;
  const int colSwzE = (((lane & 7) ^ l8) << 3);  // pre-swizzled source col
  const int NT = K >> 6;

  int pblk[2];
  pblk[0] = (lane >> 4) ^ (lane & 7);
  pblk[1] = (4 + (lane >> 4)) ^ (lane & 7);

  bf16x8 aF[8][2];
  bf16x8 bF[2][2];

  auto STAGE = [&](int s, int u) {
    if (s >= NT) return;
    const int d = s & 1;
    if (u < 2) {
      const __bf16* src = aT + (size_t)(u * 128 + wid * 16 + l8) * K + s * 64 + colSwzE;
#pragma unroll
      for (int i = 0; i < 2; ++i)
        async16(&Ab[d][u][wid * 16 + i * 8][0], src + (size_t)(i * 8) * K);
    } else {
      const __bf16* src = bT + (size_t)((u - 2) * 128 + wid * 16 + l8) * K + s * 64 + colSwzE;
#pragma unroll
      for (int i = 0; i < 2; ++i)
        async16(&Bb[d][u - 2][wid * 16 + i * 8][0], src + (size_t)(i * 8) * K);
    }
  };

  // prologue
  STAGE(0, 0); STAGE(0, 1); STAGE(0, 2); STAGE(0, 3);
  STAGE(1, 0); STAGE(1, 1);
  asm volatile("s_waitcnt vmcnt(4)" ::: "memory");
  BARRIER();

  for (int t = 0; t < NT; ++t) {
    const int d = t & 1;
    const char* pa = (const char*)&Ab[d][wr][0][0];
    const char* pb = (const char*)&Bb[d][wcn >> 1][0][0];
    const int brow = (wcn & 1) * 64;

    // stage next tile's B (slot freed at entry barrier)
    STAGE(t + 1, 2); STAGE(t + 1, 3);

    // read all A frags + B ni0-1
#pragma unroll
    for (int mi = 0; mi < 8; ++mi)
#pragma unroll
      for (int kh = 0; kh < 2; ++kh)
        aF[mi][kh] = *(const bf16x8*)(pa + (mi * 16 + (lane & 15)) * 128 + pblk[kh] * 16);
#pragma unroll
    for (int ni = 0; ni < 2; ++ni)
#pragma unroll
      for (int kh = 0; kh < 2; ++kh)
        bF[ni][kh] = *(const bf16x8*)(pb + (brow + ni * 16 + (lane & 15)) * 128 + pblk[kh] * 16);

    BARRIER();  // B1: A-slot WAR fence (all waves' A reads issued & drained)

    // stage A(t+2) into the just-freed A slot; floats across tile boundary
    STAGE(t + 2, 0); STAGE(t + 2, 1);

    __builtin_amdgcn_s_setprio(1);
#pragma unroll
    for (int mi = 0; mi < 8; ++mi)
#pragma unroll
      for (int ni = 0; ni < 2; ++ni)
#pragma unroll
        for (int kh = 0; kh < 2; ++kh)
          acc[mi][ni] = __builtin_amdgcn_mfma_f32_16x16x32_bf16(bF[ni][kh], aF[mi][kh], acc[mi][ni], 0, 0, 0);
    __builtin_amdgcn_s_setprio(0);

    // read B ni2-3, second MFMA cluster
#pragma unroll
    for (int ni = 0; ni < 2; ++ni)
#pragma unroll
      for (int kh = 0; kh < 2; ++kh)
        bF[ni][kh] = *(const bf16x8*)(pb + (brow + (2 + ni) * 16 + (lane & 15)) * 128 + pblk[kh] * 16);

    __builtin_amdgcn_s_setprio(1);
#pragma unroll
    for (int mi = 0; mi < 8; ++mi)
#pragma unroll
      for (int ni = 0; ni < 2; ++ni)
#pragma unroll
        for (int kh = 0; kh < 2; ++kh)
          acc[mi][2 + ni] = __builtin_amdgcn_mfma_f32_16x16x32_bf16(bF[ni][kh], aF[mi][kh], acc[mi][2 + ni], 0, 0, 0);
    __builtin_amdgcn_s_setprio(0);

    if (t < NT - 2) { asm volatile("s_waitcnt vmcnt(4)" ::: "memory"); }
    else            { asm volatile("s_waitcnt vmcnt(0)" ::: "memory"); }
    BARRIER();  // tile boundary
  }
}

// ---------------------------------------------------------------------------
// fc1: h = relu(xb @ w1b^T + b1) -> bf16 hb.  acc is C^T: row=n, col=t.
// ---------------------------------------------------------------------------
__global__ __launch_bounds__(512, 2) void fc1g_kernel(
    const __bf16* __restrict__ xb, int eOffA,
    const __bf16* __restrict__ w1b, int eOffB,
    const float* __restrict__ b1, __bf16* __restrict__ hb,
    int e0, int t_base, int tcap, int nbT) {
  __shared__ __bf16 Ab[2][2][128][64];
  __shared__ __bf16 Bb[2][2][128][64];
  const int nbN = Hh / 256;  // 16
  const int id = xcd_swz(blockIdx.x, gridDim.x);
  const int z = id / (nbN * nbT);
  const int rm = id % (nbN * nbT);
  const int tblk = (rm / nbN) * 256, nblk = (rm % nbN) * 256;
  const int lane = threadIdx.x & 63, wid = threadIdx.x >> 6;
  const int wr = wid >> 2, wcn = wid & 3;

  const __bf16* aT = xb + ((size_t)(eOffA + z) * Tt + t_base + tblk) * Mm;
  const __bf16* bT = w1b + ((size_t)(eOffB + z) * Hh + nblk) * Mm;

  f32x4 acc[8][4];
#pragma unroll
  for (int i = 0; i < 8; ++i)
#pragma unroll
    for (int j = 0; j < 4; ++j) acc[i][j] = (f32x4){0.f, 0.f, 0.f, 0.f};

  gemm256(aT, bT, Mm, Ab, Bb, acc);

  const float* bias = b1 + (size_t)(e0 + z) * Hh;
#pragma unroll
  for (int ni = 0; ni < 4; ++ni) {
    const int n0 = nblk + wcn * 64 + ni * 16 + ((lane >> 4) << 2);
    const f32x4 b4 = *(const f32x4*)(bias + n0);
#pragma unroll
    for (int mi = 0; mi < 8; ++mi) {
      const int trow = tblk + wr * 128 + mi * 16 + (lane & 15);
      f32x4 v = acc[mi][ni];
      bf16x4 o;
#pragma unroll
      for (int rr = 0; rr < 4; ++rr) {
        float f = v[rr] + b4[rr];
        o[rr] = (__bf16)(f > 0.f ? f : 0.f);
      }
      *(bf16x4*)(hb + ((size_t)z * tcap + trow) * Hh + n0) = o;
    }
  }
}

// ---------------------------------------------------------------------------
// fc2: out = hb @ w2t^T + b2 -> fp32 scattered to [B,E,C,M]. acc: row=m, col=t.
// ---------------------------------------------------------------------------
__global__ __launch_bounds__(512, 2) void fc2g_kernel(
    const __bf16* __restrict__ hb, int tcap,
    const __bf16* __restrict__ w2t, int eOffB,
    const float* __restrict__ b2, float* __restrict__ out,
    int e0, int t_base, int nbT) {
  __shared__ __bf16 Ab[2][2][128][64];
  __shared__ __bf16 Bb[2][2][128][64];
  const int nbN = Mm / 256;  // 4
  const int id = xcd_swz(blockIdx.x, gridDim.x);
  const int z = id / (nbN * nbT);
  const int rm = id % (nbN * nbT);
  const int tblk = (rm / nbN) * 256, nblk = (rm % nbN) * 256;
  const int lane = threadIdx.x & 63, wid = threadIdx.x >> 6;
  const int wr = wid >> 2, wcn = wid & 3;
  const int e = e0 + z;

  const __bf16* aT = hb + ((size_t)z * tcap + tblk) * Hh;
  const __bf16* bT = w2t + ((size_t)(eOffB + z) * Mm + nblk) * Hh;

  f32x4 acc[8][4];
#pragma unroll
  for (int i = 0; i < 8; ++i)
#pragma unroll
    for (int j = 0; j < 4; ++j) acc[i][j] = (f32x4){0.f, 0.f, 0.f, 0.f};

  gemm256(aT, bT, Hh, Ab, Bb, acc);

  const float* bias = b2 + (size_t)e * Mm;
#pragma unroll
  for (int ni = 0; ni < 4; ++ni) {
    const int m0 = nblk + wcn * 64 + ni * 16 + ((lane >> 4) << 2);
    const f32x4 b4 = *(const f32x4*)(bias + m0);
#pragma unroll
    for (int mi = 0; mi < 8; ++mi) {
      const int t = t_base + tblk + wr * 128 + mi * 16 + (lane & 15);
      const int bb = t >> 9, cc = t & 511;
      f32x4 v = acc[mi][ni];
#pragma unroll
      for (int rr = 0; rr < 4; ++rr) v[rr] += b4[rr];
      *(f32x4*)(out + ((((size_t)bb * Ee + e) * Cc + cc) << 10) + m0) = v;
    }
  }
}

// ---------------------------------------------------------------------------
// Prepass: x [B,E,C,M] fp32 -> xb [z][T][M] bf16 (permute fused)
// ---------------------------------------------------------------------------
__global__ __launch_bounds__(256) void cvt_x_kernel(
    const float* __restrict__ x, __bf16* __restrict__ xb, int e0) {
  size_t idx8 = (size_t)blockIdx.x * 256 + threadIdx.x;
  int m8 = (int)(idx8 & 127);
  int t = (int)((idx8 >> 7) & 2047);
  int z = (int)(idx8 >> 18);
  int b = t >> 9, c = t & 511, e = e0 + z;
  const float* src = x + ((((size_t)b * Ee + e) * Cc + c) << 10) + (m8 << 3);
  f32x4 v0 = *(const f32x4*)src;
  f32x4 v1 = *(const f32x4*)(src + 4);
  bf16x8 o;
  o[0] = (__bf16)v0[0]; o[1] = (__bf16)v0[1]; o[2] = (__bf16)v0[2]; o[3] = (__bf16)v0[3];
  o[4] = (__bf16)v1[0]; o[5] = (__bf16)v1[1]; o[6] = (__bf16)v1[2]; o[7] = (__bf16)v1[3];
  *(bf16x8*)(xb + (idx8 << 3)) = o;
}

__global__ __launch_bounds__(256) void cvt_lin_kernel(
    const float* __restrict__ in, __bf16* __restrict__ outb) {
  size_t i8 = (size_t)blockIdx.x * 256 + threadIdx.x;
  const float* src = in + (i8 << 3);
  f32x4 v0 = *(const f32x4*)src;
  f32x4 v1 = *(const f32x4*)(src + 4);
  bf16x8 o;
  o[0] = (__bf16)v0[0]; o[1] = (__bf16)v0[1]; o[2] = (__bf16)v0[2]; o[3] = (__bf16)v0[3];
  o[4] = (__bf16)v1[0]; o[5] = (__bf16)v1[1]; o[6] = (__bf16)v1[2]; o[7] = (__bf16)v1[3];
  *(bf16x8*)(outb + (i8 << 3)) = o;
}

// ---------------------------------------------------------------------------
// Prepass: W2 [E][H][M] fp32 -> W2T [z][M][H] bf16 (transpose + convert)
// ---------------------------------------------------------------------------
__global__ __launch_bounds__(256) void tr_w2_kernel(
    const float* __restrict__ w2, __bf16* __restrict__ w2t, int e0) {
  __shared__ __bf16 tile[64][68];
  const int z = blockIdx.z, e = e0 + z;
  const int m0 = blockIdx.x * 64, h0 = blockIdx.y * 64;
  const int tid = threadIdx.x;
  const int cg = tid & 15, rg = tid >> 4;
#pragma unroll
  for (int p = 0; p < 4; ++p) {
    int hl = rg + p * 16;
    f32x4 v = *(const f32x4*)(w2 + (((size_t)e * Hh + h0 + hl) << 10) + m0 + (cg << 2));
#pragma unroll
    for (int i = 0; i < 4; ++i) tile[(cg << 2) + i][hl] = (__bf16)v[i];
  }
  __syncthreads();
#pragma unroll
  for (int p = 0; p < 4; ++p) {
    int ml = rg + p * 16;
    uint2 pk = *(const uint2*)(&tile[ml][cg << 2]);
    *(uint2*)(w2t + ((size_t)z * Mm + m0 + ml) * Hh + h0 + (cg << 2)) = pk;
  }
}

// ---------------------------------------------------------------------------
extern "C" void kernel_launch(void* const* d_in, const int* in_sizes, int n_in,
                              void* d_out, int out_size, void* d_ws, size_t ws_size,
                              hipStream_t stream) {
  const float* x  = (const float*)d_in[0];
  const float* w1 = (const float*)d_in[1];
  const float* b1 = (const float*)d_in[2];
  const float* w2 = (const float*)d_in[3];
  const float* b2 = (const float*)d_in[4];
  float* out = (float*)d_out;

  const size_t xbS = (size_t)Tt * Mm * 2;  //  4 MiB / expert
  const size_t w1S = (size_t)Hh * Mm * 2;  //  8 MiB / expert
  const size_t w2S = (size_t)Mm * Hh * 2;  //  8 MiB / expert
  const size_t hbS = (size_t)Tt * Hh * 2;  // 16 MiB / expert
  char* ws = (char*)d_ws;

  if (ws_size >= Ee * (xbS + w1S + w2S + hbS)) {
    // Path A: everything resident (288 MiB). One shot.
    __bf16* xb  = (__bf16*)ws;
    __bf16* w1b = (__bf16*)(ws + Ee * xbS);
    __bf16* w2t = (__bf16*)(ws + Ee * (xbS + w1S));
    __bf16* hb  = (__bf16*)(ws + Ee * (xbS + w1S + w2S));
    cvt_x_kernel<<<Ee * 1024, 256, 0, stream>>>(x, xb, 0);
    cvt_lin_kernel<<<Ee * 2048, 256, 0, stream>>>(w1, w1b);
    tr_w2_kernel<<<dim3(Mm / 64, Hh / 64, Ee), 256, 0, stream>>>(w2, w2t, 0);
    fc1g_kernel<<<(Hh / 256) * (Tt / 256) * Ee, 512, 0, stream>>>(xb, 0, w1b, 0, b1, hb, 0, 0, Tt, Tt / 256);
    fc2g_kernel<<<(Mm / 256) * (Tt / 256) * Ee, 512, 0, stream>>>(hb, Tt, w2t, 0, b2, out, 0, 0, Tt / 256);
  } else if (ws_size >= Ee * (xbS + w1S + w2S) + hbS) {
    // Path B: all conversions resident; hb grouped.
    __bf16* xb  = (__bf16*)ws;
    __bf16* w1b = (__bf16*)(ws + Ee * xbS);
    __bf16* w2t = (__bf16*)(ws + Ee * (xbS + w1S));
    __bf16* hb  = (__bf16*)(ws + Ee * (xbS + w1S + w2S));
    int Gh = (int)((ws_size - Ee * (xbS + w1S + w2S)) / hbS);
    if (Gh > Ee) Gh = Ee;
    cvt_x_kernel<<<Ee * 1024, 256, 0, stream>>>(x, xb, 0);
    cvt_lin_kernel<<<Ee * 2048, 256, 0, stream>>>(w1, w1b);
    tr_w2_kernel<<<dim3(Mm / 64, Hh / 64, Ee), 256, 0, stream>>>(w2, w2t, 0);
    for (int e0 = 0; e0 < Ee; e0 += Gh) {
      int g = (Ee - e0) < Gh ? (Ee - e0) : Gh;
      fc1g_kernel<<<(Hh / 256) * (Tt / 256) * g, 512, 0, stream>>>(xb, e0, w1b, e0, b1, hb, e0, 0, Tt, Tt / 256);
      fc2g_kernel<<<(Mm / 256) * (Tt / 256) * g, 512, 0, stream>>>(hb, Tt, w2t, e0, b2, out, e0, 0, Tt / 256);
    }
  } else if (ws_size >= xbS + w1S + w2S + hbS) {
    // Path C: full pipeline grouped by G experts.
    int G = (int)(ws_size / (xbS + w1S + w2S + hbS));
    if (G > Ee) G = Ee;
    __bf16* xb  = (__bf16*)ws;
    __bf16* w1b = (__bf16*)(ws + (size_t)G * xbS);
    __bf16* w2t = (__bf16*)(ws + (size_t)G * (xbS + w1S));
    __bf16* hb  = (__bf16*)(ws + (size_t)G * (xbS + w1S + w2S));
    for (int e0 = 0; e0 < Ee; e0 += G) {
      int g = (Ee - e0) < G ? (Ee - e0) : G;
      cvt_x_kernel<<<g * 1024, 256, 0, stream>>>(x, xb, e0);
      cvt_lin_kernel<<<g * 2048, 256, 0, stream>>>(w1 + (size_t)e0 * Hh * Mm, w1b);
      tr_w2_kernel<<<dim3(Mm / 64, Hh / 64, g), 256, 0, stream>>>(w2, w2t, e0);
      fc1g_kernel<<<(Hh / 256) * (Tt / 256) * g, 512, 0, stream>>>(xb, 0, w1b, 0, b1, hb, e0, 0, Tt, Tt / 256);
      fc2g_kernel<<<(Mm / 256) * (Tt / 256) * g, 512, 0, stream>>>(hb, Tt, w2t, 0, b2, out, e0, 0, Tt / 256);
    }
  } else {
    // Path D: one expert, T chunked (256-row granularity).
    __bf16* xb  = (__bf16*)ws;
    __bf16* w1b = (__bf16*)(ws + xbS);
    __bf16* w2t = (__bf16*)(ws + xbS + w1S);
    __bf16* hb  = (__bf16*)(ws + xbS + w1S + w2S);
    size_t rem = ws_size > (xbS + w1S + w2S) ? ws_size - (xbS + w1S + w2S) : 0;
    int Tc = (int)(rem / ((size_t)Hh * 2)) & ~255;
    if (Tc > Tt) Tc = Tt;
    if (Tc < 256) Tc = 256;
    for (int e0 = 0; e0 < Ee; ++e0) {
      cvt_x_kernel<<<1024, 256, 0, stream>>>(x, xb, e0);
      cvt_lin_kernel<<<2048, 256, 0, stream>>>(w1 + (size_t)e0 * Hh * Mm, w1b);
      tr_w2_kernel<<<dim3(Mm / 64, Hh / 64, 1), 256, 0, stream>>>(w2, w2t, e0);
      for (int t0 = 0; t0 < Tt; t0 += Tc) {
        int tc = (Tt - t0) < Tc ? (Tt - t0) : Tc;
        fc1g_kernel<<<(Hh / 256) * (tc / 256), 512, 0, stream>>>(xb, 0, w1b, 0, b1, hb, e0, t0, Tc, tc / 256);
        fc2g_kernel<<<(Mm / 256) * (tc / 256), 512, 0, stream>>>(hb, Tc, w2t, 0, b2, out, e0, t0, tc / 256);
      }
    }
  }
}